// Round 13
// baseline (251.008 us; speedup 1.0000x reference)
//
#include <hip/hip_runtime.h>
#include <hip/hip_bf16.h>

typedef unsigned short u16;
typedef unsigned int u32;
typedef __attribute__((ext_vector_type(8))) short short8;
typedef __attribute__((ext_vector_type(4))) float float4v;

#define DEV __device__ __forceinline__

// B=2, N=2048, K=32, H=128, NODE_IN=64, EDGE_IN=48, DEPTH=3
constexpr int NN = 2048;
constexpr int BN = 4096;      // B*N
constexpr int NEDGE = 131072; // B*N*K
constexpr float SCALE_INV = 1.0f / 30.0f;
constexpr float EPS = 1e-6f;

DEV u16 f2bf(float f) {
    u32 u = __float_as_uint(f);
    u32 r = (u + 0x7fffu + ((u >> 16) & 1u)) >> 16;
    return (u16)r;
}
DEV float bf2f(u16 v) { return __uint_as_float(((u32)v) << 16); }

// ---------------- fused setup: edge_embed (blk 0..1023) + node_embed+P0/G0
// (blk 1024..1535) + weight pack (blk 1536..1550) ----------------------------
// pack slots: 0..5=(l,{W1d,W2}) ; 6..11=(layer 1|2,{W1a,W1b,W1c}) ; 12..14=W3[l]
// R13: launch_bounds (256,4) — LDS 39936*4 = 159.7KB fits 160KB; kernel is
// latency-bound (R12: VALUBusy 29%, HBM 9%, occ 28%) so +33% waves should cut dur.
__global__ __launch_bounds__(256, 4) void k_setup(
    const float* __restrict__ V, const float* __restrict__ E,
    const float* __restrict__ hS,
    const float* __restrict__ Vw_w, const float* __restrict__ Vw_b,
    const float* __restrict__ Vw_g, const float* __restrict__ Vw_b2,
    const float* __restrict__ We_w, const float* __restrict__ We_b,
    const float* __restrict__ We_g, const float* __restrict__ We_b2,
    const float* __restrict__ Lw1, const float* __restrict__ Lb1,
    const float* __restrict__ Lw2, const float* __restrict__ Lw3,
    float* __restrict__ hout, u16* __restrict__ he, u16* __restrict__ pack,
    float* __restrict__ P, float* __restrict__ G) {
    // edge: sET[48][130] f32 | sOut[128][136] bf16 ; node: sV|sHn|sSn
    __shared__ __align__(16) char sBuf[34816];
    __shared__ float sSum[128 * 5];
    __shared__ float sSq[128 * 5];
    int b = blockIdx.x;
    int t = threadIdx.x;

    if (b < 1024) {
        // ---------------- edge embed: 128 edge-rows, wave-sliced cols -------
        float* sET = (float*)sBuf;
        u16* sOut = (u16*)sBuf;
        int L = t & 63, w = t >> 6;
        size_t rowbase = (size_t)b * 128;

        const float4v* src4 = (const float4v*)(E + rowbase * 48);
        #pragma unroll
        for (int i = 0; i < 6; i++) {
            int idx4 = t + i * 256;
            int r = idx4 / 12, c4 = (idx4 - r * 12) * 4;
            float4v v = src4[idx4];
            sET[(c4 + 0) * 130 + r] = v[0];
            sET[(c4 + 1) * 130 + r] = v[1];
            sET[(c4 + 2) * 130 + r] = v[2];
            sET[(c4 + 3) * 130 + r] = v[3];
        }
        __syncthreads();

        int wcol = __builtin_amdgcn_readfirstlane(w * 32);
        float4v acc0[8], acc1[8];
        #pragma unroll
        for (int ci = 0; ci < 8; ci++) {
            float4v bb = *(const float4v*)(We_b + wcol + ci * 4);
            acc0[ci] = bb;
            acc1[ci] = bb;
        }
        #pragma unroll 4
        for (int k = 0; k < 48; k++) {
            float2 e = *(const float2*)&sET[k * 130 + 2 * L];
            const float* wK = We_w + k * 128 + wcol;
            #pragma unroll
            for (int ci = 0; ci < 8; ci++) {
                float4v wv = *(const float4v*)(wK + ci * 4);
                acc0[ci] += e.x * wv;
                acc1[ci] += e.y * wv;
            }
        }

        float s0 = 0.f, q0 = 0.f, s1 = 0.f, q1 = 0.f;
        #pragma unroll
        for (int ci = 0; ci < 8; ci++) {
            #pragma unroll
            for (int p = 0; p < 4; p++) {
                float a0 = acc0[ci][p], a1 = acc1[ci][p];
                s0 += a0; q0 += a0 * a0;
                s1 += a1; q1 += a1 * a1;
            }
        }
        sSum[(2 * L) * 5 + w] = s0;     sSq[(2 * L) * 5 + w] = q0;
        sSum[(2 * L + 1) * 5 + w] = s1; sSq[(2 * L + 1) * 5 + w] = q1;
        __syncthreads();

        float fs0 = 0.f, fq0 = 0.f, fs1 = 0.f, fq1 = 0.f;
        #pragma unroll
        for (int j = 0; j < 4; j++) {
            fs0 += sSum[(2 * L) * 5 + j];     fq0 += sSq[(2 * L) * 5 + j];
            fs1 += sSum[(2 * L + 1) * 5 + j]; fq1 += sSq[(2 * L + 1) * 5 + j];
        }
        float mu0 = fs0 * (1.0f / 128.0f), mu1 = fs1 * (1.0f / 128.0f);
        float var0 = (fq0 - 128.0f * mu0 * mu0) * (1.0f / 127.0f);
        float var1 = (fq1 - 128.0f * mu1 * mu1) * (1.0f / 127.0f);
        float inv0 = 1.0f / (sqrtf(var0) + EPS);
        float inv1 = 1.0f / (sqrtf(var1) + EPS);

        u16* out0 = &sOut[(2 * L) * 136 + wcol];
        u16* out1 = &sOut[(2 * L + 1) * 136 + wcol];
        #pragma unroll
        for (int cc = 0; cc < 4; cc++) {
            u32 w0[4], w1[4];
            #pragma unroll
            for (int p = 0; p < 4; p++) {
                int c = cc * 8 + p * 2;
                int ci = c >> 2, pc = c & 3;
                float ga = We_g[wcol + c], gb = We_g[wcol + c + 1];
                float ba = We_b2[wcol + c], bb = We_b2[wcol + c + 1];
                float x0a = ga * (acc0[ci][pc] - mu0) * inv0 + ba;
                float x0b = gb * (acc0[ci][pc + 1] - mu0) * inv0 + bb;
                float x1a = ga * (acc1[ci][pc] - mu1) * inv1 + ba;
                float x1b = gb * (acc1[ci][pc + 1] - mu1) * inv1 + bb;
                w0[p] = (u32)f2bf(x0a) | ((u32)f2bf(x0b) << 16);
                w1[p] = (u32)f2bf(x1a) | ((u32)f2bf(x1b) << 16);
            }
            *(uint4*)(out0 + cc * 8) = make_uint4(w0[0], w0[1], w0[2], w0[3]);
            *(uint4*)(out1 + cc * 8) = make_uint4(w1[0], w1[1], w1[2], w1[3]);
        }
        __syncthreads();

        uint4* dst = (uint4*)(he + rowbase * 128);
        #pragma unroll
        for (int i = 0; i < 8; i++) {
            int c = t + i * 256;
            int row = c >> 4, m = c & 15;
            dst[c] = *(const uint4*)((const char*)sBuf + row * 272 + m * 16);
        }
    } else if (b < 1536) {
        // ------- node embed + layer-0 P/G (fp32): 8 nodes per block ---------
        float* sV = (float*)sBuf;          // [8][64]
        float* sHn = ((float*)sBuf) + 512; // [8][128]
        float* sSn = ((float*)sBuf) + 1536;// [8][128]
        int nb = (b - 1024) * 8;
        #pragma unroll
        for (int i = 0; i < 2; i++) sV[t + i * 256] = V[(size_t)nb * 64 + t + i * 256];
        #pragma unroll
        for (int i = 0; i < 4; i++) sSn[t + i * 256] = hS[(size_t)nb * 128 + t + i * 256];
        __syncthreads();
        int g = t >> 5, L = t & 31;
        const float* v = &sV[g * 64];
        float a0 = Vw_b[L], a1 = Vw_b[L + 32], a2 = Vw_b[L + 64], a3 = Vw_b[L + 96];
        #pragma unroll 4
        for (int k = 0; k < 64; k++) {
            float vk = v[k];
            const float* wk = Vw_w + k * 128;
            a0 += vk * wk[L];
            a1 += vk * wk[L + 32];
            a2 += vk * wk[L + 64];
            a3 += vk * wk[L + 96];
        }
        float s = a0 + a1 + a2 + a3;
        float q = a0 * a0 + a1 * a1 + a2 * a2 + a3 * a3;
        #pragma unroll
        for (int o = 16; o > 0; o >>= 1) {
            s += __shfl_xor(s, o, 32);
            q += __shfl_xor(q, o, 32);
        }
        float mu = s * (1.0f / 128.0f);
        float var = (q - 128.0f * mu * mu) * (1.0f / 127.0f);
        float inv = 1.0f / (sqrtf(var) + EPS);
        float* outr = hout + (size_t)(nb + g) * 128;
        float o0 = Vw_g[L]      * (a0 - mu) * inv + Vw_b2[L];
        float o1 = Vw_g[L + 32] * (a1 - mu) * inv + Vw_b2[L + 32];
        float o2 = Vw_g[L + 64] * (a2 - mu) * inv + Vw_b2[L + 64];
        float o3 = Vw_g[L + 96] * (a3 - mu) * inv + Vw_b2[L + 96];
        outr[L] = o0; outr[L + 32] = o1; outr[L + 64] = o2; outr[L + 96] = o3;
        sHn[g * 128 + L] = o0;      sHn[g * 128 + L + 32] = o1;
        sHn[g * 128 + L + 64] = o2; sHn[g * 128 + L + 96] = o3;
        __syncthreads();
        int c = t & 127, pr = t >> 7;
        float p[4], gq[4];
        float b1 = Lb1[c];
        #pragma unroll
        for (int i = 0; i < 4; i++) { p[i] = b1; gq[i] = 0.f; }
        #pragma unroll 2
        for (int k = 0; k < 128; k++) {
            float wa = Lw1[k * 128 + c];
            float wb = Lw1[(128 + k) * 128 + c];
            float wc = Lw1[(256 + k) * 128 + c];
            #pragma unroll
            for (int i = 0; i < 4; i++) {
                float hk = sHn[(pr * 4 + i) * 128 + k];
                float sk = sSn[(pr * 4 + i) * 128 + k];
                p[i] += hk * wa;
                gq[i] += hk * wb + sk * wc;
            }
        }
        #pragma unroll
        for (int i = 0; i < 4; i++) {
            P[(size_t)(nb + pr * 4 + i) * 128 + c] = p[i];
            G[(size_t)(nb + pr * 4 + i) * 128 + c] = gq[i];
        }
    } else {
        // -------- pack weights into MFMA B-frag order -----------------------
        int lm = b - 1536;
        const float* src;
        if (lm < 6) {         // slots 0..5: (l, {W1d, W2})
            int l = lm >> 1, mat = lm & 1;
            src = (mat == 0) ? (Lw1 + ((size_t)l * 512 + 384) * 128)
                             : (Lw2 + (size_t)l * 16384);
        } else if (lm < 12) { // slots 6..11: (layer 1|2, {W1a, W1b, W1c})
            int idx = lm - 6, ll = idx / 3, mi = idx - ll * 3;
            src = Lw1 + (((size_t)(ll + 1) * 512) + mi * 128) * 128;
        } else {              // slots 12..14: W3 per layer
            src = Lw3 + (size_t)(lm - 12) * 16384;
        }
        u16* dst = pack + (size_t)lm * 16384;
        for (int i = 0; i < 64; i++) {
            int idx = t * 64 + i;
            int j = idx & 7, lane = (idx >> 3) & 63, s = (idx >> 9) & 3, tt = idx >> 11;
            int k = s * 32 + (lane >> 4) * 8 + j;
            int n = tt * 16 + (lane & 15);
            dst[idx] = f2bf(src[k * 128 + n]);
        }
    }
}

// ---------- per-layer edge MLP + fused post + fused next-layer P/G ---------
// GEMM1: m1 = relu(he@W1d + P[i] + G[j]) ; GEMM2: m2 = relu(m1@W2 + b2)
// masked edge-sum -> split-bf16 (4 rows only, reads guarded c16<4) ;
// dh = sM@W3 via MFMA ; h = norm(h+dh)*mask ; (if !last) next P/G via
// split-bf16 MFMA into the OTHER P/G buffer (R9 race fix).
// R13: sMhi/sMlo shrunk 16->4 rows (LDS 53.1->46.5KB, comfortable 3 blk/CU).
__global__ __launch_bounds__(256, 3) void k_edge_mlp(
    const u16* __restrict__ he, const float* __restrict__ Pcur,
    const float* __restrict__ Gcur, float* __restrict__ Pnext, float* __restrict__ Gnext,
    const int* __restrict__ Eidx, const float* __restrict__ maskp,
    const u16* __restrict__ pack, const float* __restrict__ Lb2,
    const float* __restrict__ Lb3,
    const float* __restrict__ Lng, const float* __restrict__ Lnb,
    const float* __restrict__ Lb1, const float* __restrict__ hS, int l,
    float* __restrict__ h, float* __restrict__ outp, int last) {
    __shared__ __align__(16) u16 sA[128 * 136];     // A tiles (he, then m1)
    __shared__ __align__(16) u16 sHhi[4 * 136];     // fresh h, bf16 hi
    __shared__ __align__(16) u16 sHlo[4 * 136];     // fresh h, bf16 lo
    __shared__ __align__(16) u16 sShi[4 * 136];     // hS, bf16 hi
    __shared__ __align__(16) u16 sSlo[4 * 136];     // hS, bf16 lo
    __shared__ __align__(16) u16 sMhi[4 * 136];     // masked-sum, bf16 hi
    __shared__ __align__(16) u16 sMlo[4 * 136];     // masked-sum, bf16 lo
    __shared__ int sJ[128];
    __shared__ float sVm[128];
    __shared__ float sP[4 * 128];
    __shared__ float sM[4 * 128];   // dh (fp32, from W3 MFMA)
    __shared__ float sMs[4];
    __shared__ float sredS[4][2];
    __shared__ float sredQ[4][2];
    int nb = blockIdx.x * 4;  // global node row base
    int t = threadIdx.x;

    // stage hS rows 0..3 as split bf16
    #pragma unroll
    for (int i = 0; i < 2; i++) {
        int idx = t + i * 256;
        int r = idx >> 7, c = idx & 127;
        float x = hS[(size_t)(nb + r) * 128 + c];
        u16 hb = f2bf(x);
        sShi[r * 136 + c] = hb;
        sSlo[r * 136 + c] = f2bf(x - bf2f(hb));
    }

    if (t < 128) {
        int gr = nb + (t >> 5);
        int j = Eidx[nb * 32 + t];
        int jg = (gr >> 11) * NN + j;  // add batch offset
        sJ[t] = jg;
        sVm[t] = maskp[jg];
    }
    sP[t] = Pcur[(size_t)nb * 128 + t];
    sP[t + 256] = Pcur[(size_t)nb * 128 + 256 + t];
    {   // stage he rows (contiguous 32KB) into padded LDS
        const uint4* src = (const uint4*)(he + (size_t)nb * 32 * 128);
        #pragma unroll
        for (int i = 0; i < 8; i++) {
            int idx = i * 256 + t;
            int row = idx >> 4, col = idx & 15;
            *(uint4*)(&sA[row * 136 + col * 8]) = src[idx];
        }
    }
    __syncthreads();

    // per-node mask sums
    if (t < 4) {
        float s = 0.f;
        #pragma unroll
        for (int e = 0; e < 32; e++) s += sVm[t * 32 + e];
        sMs[t] = s;
    }

    int w = t >> 6, lane = t & 63, q = lane >> 4, c16 = lane & 15;

    // ---- prefetch G-gather + own h rows (loads overlap GEMM1)
    float gv[8][2][4];
    #pragma unroll
    for (int tm = 0; tm < 8; tm++)
        #pragma unroll
        for (int tn = 0; tn < 2; tn++) {
            int n = (2 * w + tn) * 16 + c16;
            #pragma unroll
            for (int r = 0; r < 4; r++) {
                int m = tm * 16 + q * 4 + r;
                gv[tm][tn][r] = Gcur[(size_t)sJ[m] * 128 + n];
            }
        }
    int cpost = t & 127, pr = t >> 7;
    int gr0 = nb + 2 * pr, gr1 = gr0 + 1;
    float h0 = h[(size_t)gr0 * 128 + cpost];  // safe: block exclusively owns nodes
    float h1 = h[(size_t)gr1 * 128 + cpost];

    short8 Bf[2][4];
    const short8* pk1 = (const short8*)(pack + (size_t)(l * 2) * 16384);
    #pragma unroll
    for (int tn = 0; tn < 2; tn++)
        #pragma unroll
        for (int s = 0; s < 4; s++)
            Bf[tn][s] = pk1[((2 * w + tn) * 4 + s) * 64 + lane];

    float4v acc[8][2];
    #pragma unroll
    for (int tm = 0; tm < 8; tm++)
        #pragma unroll
        for (int tn = 0; tn < 2; tn++) acc[tm][tn] = (float4v){0.f, 0.f, 0.f, 0.f};

    #pragma unroll
    for (int tm = 0; tm < 8; tm++) {
        short8 a[4];
        #pragma unroll
        for (int s = 0; s < 4; s++)
            a[s] = *(const short8*)(&sA[(tm * 16 + c16) * 136 + s * 32 + q * 8]);
        #pragma unroll
        for (int s = 0; s < 4; s++) {
            acc[tm][0] = __builtin_amdgcn_mfma_f32_16x16x32_bf16(a[s], Bf[0][s], acc[tm][0], 0, 0, 0);
            acc[tm][1] = __builtin_amdgcn_mfma_f32_16x16x32_bf16(a[s], Bf[1][s], acc[tm][1], 0, 0, 0);
        }
    }
    __syncthreads();  // all waves done reading he from sA

    // epilogue1: + P[i] + G[j] (prefetched), relu, write m1 (bf16) into sA
    #pragma unroll
    for (int tm = 0; tm < 8; tm++) {
        #pragma unroll
        for (int tn = 0; tn < 2; tn++) {
            int n = (2 * w + tn) * 16 + c16;
            #pragma unroll
            for (int r = 0; r < 4; r++) {
                int m = tm * 16 + q * 4 + r;
                int g = m >> 5;
                float v = acc[tm][tn][r] + sP[g * 128 + n] + gv[tm][tn][r];
                v = v > 0.f ? v : 0.f;
                sA[m * 136 + n] = f2bf(v);
            }
        }
    }
    __syncthreads();

    // GEMM2
    const short8* pk2 = (const short8*)(pack + (size_t)(l * 2 + 1) * 16384);
    #pragma unroll
    for (int tn = 0; tn < 2; tn++)
        #pragma unroll
        for (int s = 0; s < 4; s++)
            Bf[tn][s] = pk2[((2 * w + tn) * 4 + s) * 64 + lane];
    #pragma unroll
    for (int tm = 0; tm < 8; tm++)
        #pragma unroll
        for (int tn = 0; tn < 2; tn++) acc[tm][tn] = (float4v){0.f, 0.f, 0.f, 0.f};
    #pragma unroll
    for (int tm = 0; tm < 8; tm++) {
        short8 a[4];
        #pragma unroll
        for (int s = 0; s < 4; s++)
            a[s] = *(const short8*)(&sA[(tm * 16 + c16) * 136 + s * 32 + q * 8]);
        #pragma unroll
        for (int s = 0; s < 4; s++) {
            acc[tm][0] = __builtin_amdgcn_mfma_f32_16x16x32_bf16(a[s], Bf[0][s], acc[tm][0], 0, 0, 0);
            acc[tm][1] = __builtin_amdgcn_mfma_f32_16x16x32_bf16(a[s], Bf[1][s], acc[tm][1], 0, 0, 0);
        }
    }

    // epilogue2: +b2, relu, vmask-weighted edge-sum -> split-bf16 rows 0..3
    float b2v0 = Lb2[l * 128 + (2 * w) * 16 + c16];
    float b2v1 = Lb2[l * 128 + (2 * w + 1) * 16 + c16];
    #pragma unroll
    for (int g = 0; g < 4; g++) {
        float p0 = 0.f, p1 = 0.f;
        #pragma unroll
        for (int half = 0; half < 2; half++) {
            int tm = 2 * g + half;
            #pragma unroll
            for (int r = 0; r < 4; r++) {
                int m = tm * 16 + q * 4 + r;
                float vm = sVm[m];
                float x0 = acc[tm][0][r] + b2v0; x0 = x0 > 0.f ? x0 : 0.f;
                float x1 = acc[tm][1][r] + b2v1; x1 = x1 > 0.f ? x1 : 0.f;
                p0 += vm * x0;
                p1 += vm * x1;
            }
        }
        p0 += __shfl_xor(p0, 16, 64); p0 += __shfl_xor(p0, 32, 64);
        p1 += __shfl_xor(p1, 16, 64); p1 += __shfl_xor(p1, 32, 64);
        if (lane < 32) {
            float val = (lane < 16) ? p0 : p1;
            int col = 32 * w + (lane & 31);
            u16 hb = f2bf(val);
            sMhi[g * 136 + col] = hb;
            sMlo[g * 136 + col] = f2bf(val - bf2f(hb));
        }
    }
    __syncthreads();  // sMhi/sMlo complete; sMs valid

    // ---- dh = sM @ W3 via MFMA (split-bf16 A, rows 0..3, guarded reads) ----
    {
        const short8* pk3 = (const short8*)(pack + (size_t)(12 + l) * 16384);
        float4v accW[2];
        accW[0] = (float4v){0.f, 0.f, 0.f, 0.f};
        accW[1] = (float4v){0.f, 0.f, 0.f, 0.f};
        short8 z8 = (short8){0, 0, 0, 0, 0, 0, 0, 0};
        #pragma unroll
        for (int s = 0; s < 4; s++) {
            short8 aMh = z8, aMl = z8;
            if (c16 < 4) {
                int off = c16 * 136 + s * 32 + q * 8;
                aMh = *(const short8*)&sMhi[off];
                aMl = *(const short8*)&sMlo[off];
            }
            #pragma unroll
            for (int tn = 0; tn < 2; tn++) {
                int bi = ((2 * w + tn) * 4 + s) * 64 + lane;
                short8 bW = pk3[bi];
                accW[tn] = __builtin_amdgcn_mfma_f32_16x16x32_bf16(aMl, bW, accW[tn], 0, 0, 0);
                accW[tn] = __builtin_amdgcn_mfma_f32_16x16x32_bf16(aMh, bW, accW[tn], 0, 0, 0);
            }
        }
        if (lane < 16) {
            #pragma unroll
            for (int tn = 0; tn < 2; tn++) {
                int col = (2 * w + tn) * 16 + lane;
                #pragma unroll
                for (int r = 0; r < 4; r++) sM[r * 128 + col] = accW[tn][r];
            }
        }
    }
    __syncthreads();

    // ---- post norm: x = h + (dh + msum*b3)/30 ; h = norm(x)*mask ----------
    int c = cpost;
    int g0 = 2 * pr, g1 = g0 + 1;
    float b3 = Lb3[l * 128 + c];
    float gg = Lng[l * 128 + c];
    float bn = Lnb[l * 128 + c];
    float x0 = h0 + (sM[g0 * 128 + c] + sMs[g0] * b3) * SCALE_INV;
    float x1 = h1 + (sM[g1 * 128 + c] + sMs[g1] * b3) * SCALE_INV;
    float s0 = x0, s1 = x1, q0 = x0 * x0, q1 = x1 * x1;
    #pragma unroll
    for (int o = 32; o > 0; o >>= 1) {
        s0 += __shfl_xor(s0, o, 64); q0 += __shfl_xor(q0, o, 64);
        s1 += __shfl_xor(s1, o, 64); q1 += __shfl_xor(q1, o, 64);
    }
    if (lane == 0) {
        sredS[w][0] = s0; sredS[w][1] = s1;
        sredQ[w][0] = q0; sredQ[w][1] = q1;
    }
    __syncthreads();
    int wb = 2 * pr;
    float S0 = sredS[wb][0] + sredS[wb + 1][0];
    float S1 = sredS[wb][1] + sredS[wb + 1][1];
    float Q0 = sredQ[wb][0] + sredQ[wb + 1][0];
    float Q1 = sredQ[wb][1] + sredQ[wb + 1][1];
    float mu0 = S0 * (1.0f / 128.0f), mu1 = S1 * (1.0f / 128.0f);
    float var0 = (Q0 - 128.0f * mu0 * mu0) * (1.0f / 127.0f);
    float var1 = (Q1 - 128.0f * mu1 * mu1) * (1.0f / 127.0f);
    float m0 = maskp[gr0], m1v = maskp[gr1];
    float o0 = (gg * (x0 - mu0) / (sqrtf(var0) + EPS) + bn) * m0;
    float o1 = (gg * (x1 - mu1) / (sqrtf(var1) + EPS) + bn) * m1v;
    h[(size_t)gr0 * 128 + c] = o0;
    h[(size_t)gr1 * 128 + c] = o1;
    if (last) {
        outp[(size_t)gr0 * 128 + c] = o0;
        outp[(size_t)gr1 * 128 + c] = o1;
        return;
    }

    // ---- next-layer P/G via MFMA with split-bf16 A -------------------------
    {
        u16 hb0 = f2bf(o0);
        sHhi[g0 * 136 + c] = hb0;
        sHlo[g0 * 136 + c] = f2bf(o0 - bf2f(hb0));
        u16 hb1 = f2bf(o1);
        sHhi[g1 * 136 + c] = hb1;
        sHlo[g1 * 136 + c] = f2bf(o1 - bf2f(hb1));
    }
    __syncthreads();
    {
        const short8* pkA = (const short8*)(pack + (size_t)(6 + l * 3 + 0) * 16384);
        const short8* pkB = (const short8*)(pack + (size_t)(6 + l * 3 + 1) * 16384);
        const short8* pkC = (const short8*)(pack + (size_t)(6 + l * 3 + 2) * 16384);
        float4v accP[2], accG[2];
        #pragma unroll
        for (int tn = 0; tn < 2; tn++) {
            accP[tn] = (float4v){0.f, 0.f, 0.f, 0.f};
            accG[tn] = (float4v){0.f, 0.f, 0.f, 0.f};
        }
        short8 z8 = (short8){0, 0, 0, 0, 0, 0, 0, 0};
        #pragma unroll
        for (int s = 0; s < 4; s++) {
            short8 aHh = z8, aHl = z8, aSh = z8, aSl = z8;
            if (c16 < 4) {
                int off = c16 * 136 + s * 32 + q * 8;
                aHh = *(const short8*)&sHhi[off];
                aHl = *(const short8*)&sHlo[off];
                aSh = *(const short8*)&sShi[off];
                aSl = *(const short8*)&sSlo[off];
            }
            #pragma unroll
            for (int tn = 0; tn < 2; tn++) {
                int bi = ((2 * w + tn) * 4 + s) * 64 + lane;
                short8 bA = pkA[bi], bB = pkB[bi], bC = pkC[bi];
                accP[tn] = __builtin_amdgcn_mfma_f32_16x16x32_bf16(aHl, bA, accP[tn], 0, 0, 0);
                accP[tn] = __builtin_amdgcn_mfma_f32_16x16x32_bf16(aHh, bA, accP[tn], 0, 0, 0);
                accG[tn] = __builtin_amdgcn_mfma_f32_16x16x32_bf16(aHl, bB, accG[tn], 0, 0, 0);
                accG[tn] = __builtin_amdgcn_mfma_f32_16x16x32_bf16(aHh, bB, accG[tn], 0, 0, 0);
                accG[tn] = __builtin_amdgcn_mfma_f32_16x16x32_bf16(aSl, bC, accG[tn], 0, 0, 0);
                accG[tn] = __builtin_amdgcn_mfma_f32_16x16x32_bf16(aSh, bC, accG[tn], 0, 0, 0);
            }
        }
        if (lane < 16) {
            #pragma unroll
            for (int tn = 0; tn < 2; tn++) {
                int col = (2 * w + tn) * 16 + lane;
                float b1v = Lb1[(l + 1) * 128 + col];
                #pragma unroll
                for (int r = 0; r < 4; r++) {
                    Pnext[(size_t)(nb + r) * 128 + col] = accP[tn][r] + b1v;
                    Gnext[(size_t)(nb + r) * 128 + col] = accG[tn][r];
                }
            }
        }
    }
}

extern "C" void kernel_launch(void* const* d_in, const int* in_sizes, int n_in,
                              void* d_out, int out_size, void* d_ws, size_t ws_size,
                              hipStream_t stream) {
    const float* V     = (const float*)d_in[0];
    const float* E     = (const float*)d_in[1];
    const float* hS    = (const float*)d_in[2];
    const int*   Eidx  = (const int*)d_in[3];
    const float* maskp = (const float*)d_in[4];
    const float* Wv_w  = (const float*)d_in[5];
    const float* Wv_b  = (const float*)d_in[6];
    const float* Wv_g  = (const float*)d_in[7];
    const float* Wv_b2 = (const float*)d_in[8];
    const float* We_w  = (const float*)d_in[9];
    const float* We_b  = (const float*)d_in[10];
    const float* We_g  = (const float*)d_in[11];
    const float* We_b2 = (const float*)d_in[12];
    const float* Lw1   = (const float*)d_in[13];
    const float* Lb1   = (const float*)d_in[14];
    const float* Lw2   = (const float*)d_in[15];
    const float* Lb2   = (const float*)d_in[16];
    const float* Lw3   = (const float*)d_in[17];
    const float* Lb3   = (const float*)d_in[18];
    const float* Ln_g  = (const float*)d_in[19];
    const float* Ln_b  = (const float*)d_in[20];

    char* ws = (char*)d_ws;
    float* h    = (float*)ws; ws += (size_t)BN * 128 * 4;
    float* P0   = (float*)ws; ws += (size_t)BN * 128 * 4;
    float* G0   = (float*)ws; ws += (size_t)BN * 128 * 4;
    float* P1   = (float*)ws; ws += (size_t)BN * 128 * 4;
    float* G1   = (float*)ws; ws += (size_t)BN * 128 * 4;
    u16*   he   = (u16*)ws;   ws += (size_t)NEDGE * 128 * 2;
    u16*   pack = (u16*)ws;   ws += (size_t)15 * 16384 * 2;

    k_setup<<<1551, 256, 0, stream>>>(V, E, hS, Wv_w, Wv_b, Wv_g, Wv_b2,
                                      We_w, We_b, We_g, We_b2, Lw1, Lb1, Lw2, Lw3,
                                      h, he, pack, P0, G0);
    for (int l = 0; l < 3; l++) {
        const float* Pc = (l & 1) ? P1 : P0;
        const float* Gc = (l & 1) ? G1 : G0;
        float* Pn = (l & 1) ? P0 : P1;
        float* Gn = (l & 1) ? G0 : G1;
        k_edge_mlp<<<BN / 4, 256, 0, stream>>>(he, Pc, Gc, Pn, Gn,
                                               Eidx, maskp, pack, Lb2,
                                               Lb3, Ln_g, Ln_b, Lb1, hS, l,
                                               h, (float*)d_out, l == 2);
    }
}

// Round 14
// 240.044 us; speedup vs baseline: 1.0457x; 1.0457x over previous
//
#include <hip/hip_runtime.h>
#include <hip/hip_bf16.h>

typedef unsigned short u16;
typedef unsigned int u32;
typedef __attribute__((ext_vector_type(8))) short short8;
typedef __attribute__((ext_vector_type(4))) float float4v;

#define DEV __device__ __forceinline__

// B=2, N=2048, K=32, H=128, NODE_IN=64, EDGE_IN=48, DEPTH=3
constexpr int NN = 2048;
constexpr int BN = 4096;      // B*N
constexpr int NEDGE = 131072; // B*N*K
constexpr float SCALE_INV = 1.0f / 30.0f;
constexpr float EPS = 1e-6f;

DEV u16 f2bf(float f) {
    u32 u = __float_as_uint(f);
    u32 r = (u + 0x7fffu + ((u >> 16) & 1u)) >> 16;
    return (u16)r;
}
DEV float bf2f(u16 v) { return __uint_as_float(((u32)v) << 16); }

// ---------------- fused setup: edge_embed (blk 0..1023) + node_embed+P0/G0
// (blk 1024..1535) + weight pack (blk 1536..1550) ----------------------------
// pack slots: 0..5=(l,{W1d,W2}) ; 6..11=(layer 1|2,{W1a,W1b,W1c}) ; 12..14=W3[l]
// R13-validated: (256,4) bounds + unroll-4 cut steady-state 72->57us.
__global__ __launch_bounds__(256, 4) void k_setup(
    const float* __restrict__ V, const float* __restrict__ E,
    const float* __restrict__ hS,
    const float* __restrict__ Vw_w, const float* __restrict__ Vw_b,
    const float* __restrict__ Vw_g, const float* __restrict__ Vw_b2,
    const float* __restrict__ We_w, const float* __restrict__ We_b,
    const float* __restrict__ We_g, const float* __restrict__ We_b2,
    const float* __restrict__ Lw1, const float* __restrict__ Lb1,
    const float* __restrict__ Lw2, const float* __restrict__ Lw3,
    float* __restrict__ hout, u16* __restrict__ he, u16* __restrict__ pack,
    float* __restrict__ P, float* __restrict__ G) {
    // edge: sET[48][130] f32 | sOut[128][136] bf16 ; node: sV|sHn|sSn
    __shared__ __align__(16) char sBuf[34816];
    __shared__ float sSum[128 * 5];
    __shared__ float sSq[128 * 5];
    int b = blockIdx.x;
    int t = threadIdx.x;

    if (b < 1024) {
        // ---------------- edge embed: 128 edge-rows, wave-sliced cols -------
        float* sET = (float*)sBuf;
        u16* sOut = (u16*)sBuf;
        int L = t & 63, w = t >> 6;
        size_t rowbase = (size_t)b * 128;

        const float4v* src4 = (const float4v*)(E + rowbase * 48);
        #pragma unroll
        for (int i = 0; i < 6; i++) {
            int idx4 = t + i * 256;
            int r = idx4 / 12, c4 = (idx4 - r * 12) * 4;
            float4v v = src4[idx4];
            sET[(c4 + 0) * 130 + r] = v[0];
            sET[(c4 + 1) * 130 + r] = v[1];
            sET[(c4 + 2) * 130 + r] = v[2];
            sET[(c4 + 3) * 130 + r] = v[3];
        }
        __syncthreads();

        int wcol = __builtin_amdgcn_readfirstlane(w * 32);
        float4v acc0[8], acc1[8];
        #pragma unroll
        for (int ci = 0; ci < 8; ci++) {
            float4v bb = *(const float4v*)(We_b + wcol + ci * 4);
            acc0[ci] = bb;
            acc1[ci] = bb;
        }
        #pragma unroll 4
        for (int k = 0; k < 48; k++) {
            float2 e = *(const float2*)&sET[k * 130 + 2 * L];
            const float* wK = We_w + k * 128 + wcol;
            #pragma unroll
            for (int ci = 0; ci < 8; ci++) {
                float4v wv = *(const float4v*)(wK + ci * 4);
                acc0[ci] += e.x * wv;
                acc1[ci] += e.y * wv;
            }
        }

        float s0 = 0.f, q0 = 0.f, s1 = 0.f, q1 = 0.f;
        #pragma unroll
        for (int ci = 0; ci < 8; ci++) {
            #pragma unroll
            for (int p = 0; p < 4; p++) {
                float a0 = acc0[ci][p], a1 = acc1[ci][p];
                s0 += a0; q0 += a0 * a0;
                s1 += a1; q1 += a1 * a1;
            }
        }
        sSum[(2 * L) * 5 + w] = s0;     sSq[(2 * L) * 5 + w] = q0;
        sSum[(2 * L + 1) * 5 + w] = s1; sSq[(2 * L + 1) * 5 + w] = q1;
        __syncthreads();

        float fs0 = 0.f, fq0 = 0.f, fs1 = 0.f, fq1 = 0.f;
        #pragma unroll
        for (int j = 0; j < 4; j++) {
            fs0 += sSum[(2 * L) * 5 + j];     fq0 += sSq[(2 * L) * 5 + j];
            fs1 += sSum[(2 * L + 1) * 5 + j]; fq1 += sSq[(2 * L + 1) * 5 + j];
        }
        float mu0 = fs0 * (1.0f / 128.0f), mu1 = fs1 * (1.0f / 128.0f);
        float var0 = (fq0 - 128.0f * mu0 * mu0) * (1.0f / 127.0f);
        float var1 = (fq1 - 128.0f * mu1 * mu1) * (1.0f / 127.0f);
        float inv0 = 1.0f / (sqrtf(var0) + EPS);
        float inv1 = 1.0f / (sqrtf(var1) + EPS);

        u16* out0 = &sOut[(2 * L) * 136 + wcol];
        u16* out1 = &sOut[(2 * L + 1) * 136 + wcol];
        #pragma unroll
        for (int cc = 0; cc < 4; cc++) {
            u32 w0[4], w1[4];
            #pragma unroll
            for (int p = 0; p < 4; p++) {
                int c = cc * 8 + p * 2;
                int ci = c >> 2, pc = c & 3;
                float ga = We_g[wcol + c], gb = We_g[wcol + c + 1];
                float ba = We_b2[wcol + c], bb = We_b2[wcol + c + 1];
                float x0a = ga * (acc0[ci][pc] - mu0) * inv0 + ba;
                float x0b = gb * (acc0[ci][pc + 1] - mu0) * inv0 + bb;
                float x1a = ga * (acc1[ci][pc] - mu1) * inv1 + ba;
                float x1b = gb * (acc1[ci][pc + 1] - mu1) * inv1 + bb;
                w0[p] = (u32)f2bf(x0a) | ((u32)f2bf(x0b) << 16);
                w1[p] = (u32)f2bf(x1a) | ((u32)f2bf(x1b) << 16);
            }
            *(uint4*)(out0 + cc * 8) = make_uint4(w0[0], w0[1], w0[2], w0[3]);
            *(uint4*)(out1 + cc * 8) = make_uint4(w1[0], w1[1], w1[2], w1[3]);
        }
        __syncthreads();

        uint4* dst = (uint4*)(he + rowbase * 128);
        #pragma unroll
        for (int i = 0; i < 8; i++) {
            int c = t + i * 256;
            int row = c >> 4, m = c & 15;
            dst[c] = *(const uint4*)((const char*)sBuf + row * 272 + m * 16);
        }
    } else if (b < 1536) {
        // ------- node embed + layer-0 P/G (fp32): 8 nodes per block ---------
        float* sV = (float*)sBuf;          // [8][64]
        float* sHn = ((float*)sBuf) + 512; // [8][128]
        float* sSn = ((float*)sBuf) + 1536;// [8][128]
        int nb = (b - 1024) * 8;
        #pragma unroll
        for (int i = 0; i < 2; i++) sV[t + i * 256] = V[(size_t)nb * 64 + t + i * 256];
        #pragma unroll
        for (int i = 0; i < 4; i++) sSn[t + i * 256] = hS[(size_t)nb * 128 + t + i * 256];
        __syncthreads();
        int g = t >> 5, L = t & 31;
        const float* v = &sV[g * 64];
        float a0 = Vw_b[L], a1 = Vw_b[L + 32], a2 = Vw_b[L + 64], a3 = Vw_b[L + 96];
        #pragma unroll 4
        for (int k = 0; k < 64; k++) {
            float vk = v[k];
            const float* wk = Vw_w + k * 128;
            a0 += vk * wk[L];
            a1 += vk * wk[L + 32];
            a2 += vk * wk[L + 64];
            a3 += vk * wk[L + 96];
        }
        float s = a0 + a1 + a2 + a3;
        float q = a0 * a0 + a1 * a1 + a2 * a2 + a3 * a3;
        #pragma unroll
        for (int o = 16; o > 0; o >>= 1) {
            s += __shfl_xor(s, o, 32);
            q += __shfl_xor(q, o, 32);
        }
        float mu = s * (1.0f / 128.0f);
        float var = (q - 128.0f * mu * mu) * (1.0f / 127.0f);
        float inv = 1.0f / (sqrtf(var) + EPS);
        float* outr = hout + (size_t)(nb + g) * 128;
        float o0 = Vw_g[L]      * (a0 - mu) * inv + Vw_b2[L];
        float o1 = Vw_g[L + 32] * (a1 - mu) * inv + Vw_b2[L + 32];
        float o2 = Vw_g[L + 64] * (a2 - mu) * inv + Vw_b2[L + 64];
        float o3 = Vw_g[L + 96] * (a3 - mu) * inv + Vw_b2[L + 96];
        outr[L] = o0; outr[L + 32] = o1; outr[L + 64] = o2; outr[L + 96] = o3;
        sHn[g * 128 + L] = o0;      sHn[g * 128 + L + 32] = o1;
        sHn[g * 128 + L + 64] = o2; sHn[g * 128 + L + 96] = o3;
        __syncthreads();
        int c = t & 127, pr = t >> 7;
        float p[4], gq[4];
        float b1 = Lb1[c];
        #pragma unroll
        for (int i = 0; i < 4; i++) { p[i] = b1; gq[i] = 0.f; }
        #pragma unroll 2
        for (int k = 0; k < 128; k++) {
            float wa = Lw1[k * 128 + c];
            float wb = Lw1[(128 + k) * 128 + c];
            float wc = Lw1[(256 + k) * 128 + c];
            #pragma unroll
            for (int i = 0; i < 4; i++) {
                float hk = sHn[(pr * 4 + i) * 128 + k];
                float sk = sSn[(pr * 4 + i) * 128 + k];
                p[i] += hk * wa;
                gq[i] += hk * wb + sk * wc;
            }
        }
        #pragma unroll
        for (int i = 0; i < 4; i++) {
            P[(size_t)(nb + pr * 4 + i) * 128 + c] = p[i];
            G[(size_t)(nb + pr * 4 + i) * 128 + c] = gq[i];
        }
    } else {
        // -------- pack weights into MFMA B-frag order -----------------------
        int lm = b - 1536;
        const float* src;
        if (lm < 6) {         // slots 0..5: (l, {W1d, W2})
            int l = lm >> 1, mat = lm & 1;
            src = (mat == 0) ? (Lw1 + ((size_t)l * 512 + 384) * 128)
                             : (Lw2 + (size_t)l * 16384);
        } else if (lm < 12) { // slots 6..11: (layer 1|2, {W1a, W1b, W1c})
            int idx = lm - 6, ll = idx / 3, mi = idx - ll * 3;
            src = Lw1 + (((size_t)(ll + 1) * 512) + mi * 128) * 128;
        } else {              // slots 12..14: W3 per layer
            src = Lw3 + (size_t)(lm - 12) * 16384;
        }
        u16* dst = pack + (size_t)lm * 16384;
        for (int i = 0; i < 64; i++) {
            int idx = t * 64 + i;
            int j = idx & 7, lane = (idx >> 3) & 63, s = (idx >> 9) & 3, tt = idx >> 11;
            int k = s * 32 + (lane >> 4) * 8 + j;
            int n = tt * 16 + (lane & 15);
            dst[idx] = f2bf(src[k * 128 + n]);
        }
    }
}

// ---------- per-layer edge MLP + fused post + fused next-layer P/G ---------
// GEMM1: m1 = relu(he@W1d + P[i] + G[j]) ; GEMM2: m2 = relu(m1@W2 + b2)
// masked edge-sum -> split-bf16 M=16 A-frags (rows 4..15 zeroed, reads
// UNGUARDED — R13's c16<4 guard in the unrolled W3 loop cost ~5us/dispatch);
// dh = sM@W3 via MFMA ; h = norm(h+dh)*mask ; (if !last) next P/G via
// split-bf16 MFMA into the OTHER P/G buffer (R9 race fix).
__global__ __launch_bounds__(256, 3) void k_edge_mlp(
    const u16* __restrict__ he, const float* __restrict__ Pcur,
    const float* __restrict__ Gcur, float* __restrict__ Pnext, float* __restrict__ Gnext,
    const int* __restrict__ Eidx, const float* __restrict__ maskp,
    const u16* __restrict__ pack, const float* __restrict__ Lb2,
    const float* __restrict__ Lb3,
    const float* __restrict__ Lng, const float* __restrict__ Lnb,
    const float* __restrict__ Lb1, const float* __restrict__ hS, int l,
    float* __restrict__ h, float* __restrict__ outp, int last) {
    __shared__ __align__(16) u16 sA[128 * 136];     // A tiles (he, then m1)
    __shared__ __align__(16) u16 sHhi[4 * 136];     // fresh h, bf16 hi
    __shared__ __align__(16) u16 sHlo[4 * 136];     // fresh h, bf16 lo
    __shared__ __align__(16) u16 sShi[4 * 136];     // hS, bf16 hi
    __shared__ __align__(16) u16 sSlo[4 * 136];     // hS, bf16 lo
    __shared__ __align__(16) u16 sMhi[16 * 136];    // masked-sum A-frag, hi
    __shared__ __align__(16) u16 sMlo[16 * 136];    // masked-sum A-frag, lo
    __shared__ int sJ[128];
    __shared__ float sVm[128];
    __shared__ float sP[4 * 128];
    __shared__ float sM[4 * 128];   // dh (fp32, from W3 MFMA)
    __shared__ float sMs[4];
    __shared__ float sredS[4][2];
    __shared__ float sredQ[4][2];
    int nb = blockIdx.x * 4;  // global node row base
    int t = threadIdx.x;

    // zero pad-rows 4..15 of the masked-sum A-frag buffers
    for (int i = 4 * 136 + t; i < 16 * 136; i += 256) {
        sMhi[i] = 0;
        sMlo[i] = 0;
    }
    // stage hS rows 0..3 as split bf16
    #pragma unroll
    for (int i = 0; i < 2; i++) {
        int idx = t + i * 256;
        int r = idx >> 7, c = idx & 127;
        float x = hS[(size_t)(nb + r) * 128 + c];
        u16 hb = f2bf(x);
        sShi[r * 136 + c] = hb;
        sSlo[r * 136 + c] = f2bf(x - bf2f(hb));
    }

    if (t < 128) {
        int gr = nb + (t >> 5);
        int j = Eidx[nb * 32 + t];
        int jg = (gr >> 11) * NN + j;  // add batch offset
        sJ[t] = jg;
        sVm[t] = maskp[jg];
    }
    sP[t] = Pcur[(size_t)nb * 128 + t];
    sP[t + 256] = Pcur[(size_t)nb * 128 + 256 + t];
    {   // stage he rows (contiguous 32KB) into padded LDS
        const uint4* src = (const uint4*)(he + (size_t)nb * 32 * 128);
        #pragma unroll
        for (int i = 0; i < 8; i++) {
            int idx = i * 256 + t;
            int row = idx >> 4, col = idx & 15;
            *(uint4*)(&sA[row * 136 + col * 8]) = src[idx];
        }
    }
    __syncthreads();

    // per-node mask sums
    if (t < 4) {
        float s = 0.f;
        #pragma unroll
        for (int e = 0; e < 32; e++) s += sVm[t * 32 + e];
        sMs[t] = s;
    }

    int w = t >> 6, lane = t & 63, q = lane >> 4, c16 = lane & 15;

    // ---- prefetch G-gather + own h rows (loads overlap GEMM1)
    float gv[8][2][4];
    #pragma unroll
    for (int tm = 0; tm < 8; tm++)
        #pragma unroll
        for (int tn = 0; tn < 2; tn++) {
            int n = (2 * w + tn) * 16 + c16;
            #pragma unroll
            for (int r = 0; r < 4; r++) {
                int m = tm * 16 + q * 4 + r;
                gv[tm][tn][r] = Gcur[(size_t)sJ[m] * 128 + n];
            }
        }
    int cpost = t & 127, pr = t >> 7;
    int gr0 = nb + 2 * pr, gr1 = gr0 + 1;
    float h0 = h[(size_t)gr0 * 128 + cpost];  // safe: block exclusively owns nodes
    float h1 = h[(size_t)gr1 * 128 + cpost];

    short8 Bf[2][4];
    const short8* pk1 = (const short8*)(pack + (size_t)(l * 2) * 16384);
    #pragma unroll
    for (int tn = 0; tn < 2; tn++)
        #pragma unroll
        for (int s = 0; s < 4; s++)
            Bf[tn][s] = pk1[((2 * w + tn) * 4 + s) * 64 + lane];

    float4v acc[8][2];
    #pragma unroll
    for (int tm = 0; tm < 8; tm++)
        #pragma unroll
        for (int tn = 0; tn < 2; tn++) acc[tm][tn] = (float4v){0.f, 0.f, 0.f, 0.f};

    #pragma unroll
    for (int tm = 0; tm < 8; tm++) {
        short8 a[4];
        #pragma unroll
        for (int s = 0; s < 4; s++)
            a[s] = *(const short8*)(&sA[(tm * 16 + c16) * 136 + s * 32 + q * 8]);
        #pragma unroll
        for (int s = 0; s < 4; s++) {
            acc[tm][0] = __builtin_amdgcn_mfma_f32_16x16x32_bf16(a[s], Bf[0][s], acc[tm][0], 0, 0, 0);
            acc[tm][1] = __builtin_amdgcn_mfma_f32_16x16x32_bf16(a[s], Bf[1][s], acc[tm][1], 0, 0, 0);
        }
    }
    __syncthreads();  // all waves done reading he from sA

    // epilogue1: + P[i] + G[j] (prefetched), relu, write m1 (bf16) into sA
    #pragma unroll
    for (int tm = 0; tm < 8; tm++) {
        #pragma unroll
        for (int tn = 0; tn < 2; tn++) {
            int n = (2 * w + tn) * 16 + c16;
            #pragma unroll
            for (int r = 0; r < 4; r++) {
                int m = tm * 16 + q * 4 + r;
                int g = m >> 5;
                float v = acc[tm][tn][r] + sP[g * 128 + n] + gv[tm][tn][r];
                v = v > 0.f ? v : 0.f;
                sA[m * 136 + n] = f2bf(v);
            }
        }
    }
    __syncthreads();

    // GEMM2
    const short8* pk2 = (const short8*)(pack + (size_t)(l * 2 + 1) * 16384);
    #pragma unroll
    for (int tn = 0; tn < 2; tn++)
        #pragma unroll
        for (int s = 0; s < 4; s++)
            Bf[tn][s] = pk2[((2 * w + tn) * 4 + s) * 64 + lane];
    #pragma unroll
    for (int tm = 0; tm < 8; tm++)
        #pragma unroll
        for (int tn = 0; tn < 2; tn++) acc[tm][tn] = (float4v){0.f, 0.f, 0.f, 0.f};
    #pragma unroll
    for (int tm = 0; tm < 8; tm++) {
        short8 a[4];
        #pragma unroll
        for (int s = 0; s < 4; s++)
            a[s] = *(const short8*)(&sA[(tm * 16 + c16) * 136 + s * 32 + q * 8]);
        #pragma unroll
        for (int s = 0; s < 4; s++) {
            acc[tm][0] = __builtin_amdgcn_mfma_f32_16x16x32_bf16(a[s], Bf[0][s], acc[tm][0], 0, 0, 0);
            acc[tm][1] = __builtin_amdgcn_mfma_f32_16x16x32_bf16(a[s], Bf[1][s], acc[tm][1], 0, 0, 0);
        }
    }

    // epilogue2: +b2, relu, vmask-weighted edge-sum -> split-bf16 rows 0..3
    float b2v0 = Lb2[l * 128 + (2 * w) * 16 + c16];
    float b2v1 = Lb2[l * 128 + (2 * w + 1) * 16 + c16];
    #pragma unroll
    for (int g = 0; g < 4; g++) {
        float p0 = 0.f, p1 = 0.f;
        #pragma unroll
        for (int half = 0; half < 2; half++) {
            int tm = 2 * g + half;
            #pragma unroll
            for (int r = 0; r < 4; r++) {
                int m = tm * 16 + q * 4 + r;
                float vm = sVm[m];
                float x0 = acc[tm][0][r] + b2v0; x0 = x0 > 0.f ? x0 : 0.f;
                float x1 = acc[tm][1][r] + b2v1; x1 = x1 > 0.f ? x1 : 0.f;
                p0 += vm * x0;
                p1 += vm * x1;
            }
        }
        p0 += __shfl_xor(p0, 16, 64); p0 += __shfl_xor(p0, 32, 64);
        p1 += __shfl_xor(p1, 16, 64); p1 += __shfl_xor(p1, 32, 64);
        if (lane < 32) {
            float val = (lane < 16) ? p0 : p1;
            int col = 32 * w + (lane & 31);
            u16 hb = f2bf(val);
            sMhi[g * 136 + col] = hb;
            sMlo[g * 136 + col] = f2bf(val - bf2f(hb));
        }
    }
    __syncthreads();  // sMhi/sMlo complete; sMs valid

    // ---- dh = sM @ W3 via MFMA (split-bf16 A, M=16, rows 0..3 valid) -------
    {
        const short8* pk3 = (const short8*)(pack + (size_t)(12 + l) * 16384);
        float4v accW[2];
        accW[0] = (float4v){0.f, 0.f, 0.f, 0.f};
        accW[1] = (float4v){0.f, 0.f, 0.f, 0.f};
        #pragma unroll
        for (int s = 0; s < 4; s++) {
            int off = c16 * 136 + s * 32 + q * 8;
            short8 aMh = *(const short8*)&sMhi[off];
            short8 aMl = *(const short8*)&sMlo[off];
            #pragma unroll
            for (int tn = 0; tn < 2; tn++) {
                int bi = ((2 * w + tn) * 4 + s) * 64 + lane;
                short8 bW = pk3[bi];
                accW[tn] = __builtin_amdgcn_mfma_f32_16x16x32_bf16(aMl, bW, accW[tn], 0, 0, 0);
                accW[tn] = __builtin_amdgcn_mfma_f32_16x16x32_bf16(aMh, bW, accW[tn], 0, 0, 0);
            }
        }
        if (lane < 16) {
            #pragma unroll
            for (int tn = 0; tn < 2; tn++) {
                int col = (2 * w + tn) * 16 + lane;
                #pragma unroll
                for (int r = 0; r < 4; r++) sM[r * 128 + col] = accW[tn][r];
            }
        }
    }
    __syncthreads();

    // ---- post norm: x = h + (dh + msum*b3)/30 ; h = norm(x)*mask ----------
    int c = cpost;
    int g0 = 2 * pr, g1 = g0 + 1;
    float b3 = Lb3[l * 128 + c];
    float gg = Lng[l * 128 + c];
    float bn = Lnb[l * 128 + c];
    float x0 = h0 + (sM[g0 * 128 + c] + sMs[g0] * b3) * SCALE_INV;
    float x1 = h1 + (sM[g1 * 128 + c] + sMs[g1] * b3) * SCALE_INV;
    float s0 = x0, s1 = x1, q0 = x0 * x0, q1 = x1 * x1;
    #pragma unroll
    for (int o = 32; o > 0; o >>= 1) {
        s0 += __shfl_xor(s0, o, 64); q0 += __shfl_xor(q0, o, 64);
        s1 += __shfl_xor(s1, o, 64); q1 += __shfl_xor(q1, o, 64);
    }
    if (lane == 0) {
        sredS[w][0] = s0; sredS[w][1] = s1;
        sredQ[w][0] = q0; sredQ[w][1] = q1;
    }
    __syncthreads();
    int wb = 2 * pr;
    float S0 = sredS[wb][0] + sredS[wb + 1][0];
    float S1 = sredS[wb][1] + sredS[wb + 1][1];
    float Q0 = sredQ[wb][0] + sredQ[wb + 1][0];
    float Q1 = sredQ[wb][1] + sredQ[wb + 1][1];
    float mu0 = S0 * (1.0f / 128.0f), mu1 = S1 * (1.0f / 128.0f);
    float var0 = (Q0 - 128.0f * mu0 * mu0) * (1.0f / 127.0f);
    float var1 = (Q1 - 128.0f * mu1 * mu1) * (1.0f / 127.0f);
    float m0 = maskp[gr0], m1v = maskp[gr1];
    float o0 = (gg * (x0 - mu0) / (sqrtf(var0) + EPS) + bn) * m0;
    float o1 = (gg * (x1 - mu1) / (sqrtf(var1) + EPS) + bn) * m1v;
    h[(size_t)gr0 * 128 + c] = o0;
    h[(size_t)gr1 * 128 + c] = o1;
    if (last) {
        outp[(size_t)gr0 * 128 + c] = o0;
        outp[(size_t)gr1 * 128 + c] = o1;
        return;
    }

    // ---- next-layer P/G via MFMA with split-bf16 A -------------------------
    {
        u16 hb0 = f2bf(o0);
        sHhi[g0 * 136 + c] = hb0;
        sHlo[g0 * 136 + c] = f2bf(o0 - bf2f(hb0));
        u16 hb1 = f2bf(o1);
        sHhi[g1 * 136 + c] = hb1;
        sHlo[g1 * 136 + c] = f2bf(o1 - bf2f(hb1));
    }
    __syncthreads();
    {
        const short8* pkA = (const short8*)(pack + (size_t)(6 + l * 3 + 0) * 16384);
        const short8* pkB = (const short8*)(pack + (size_t)(6 + l * 3 + 1) * 16384);
        const short8* pkC = (const short8*)(pack + (size_t)(6 + l * 3 + 2) * 16384);
        float4v accP[2], accG[2];
        #pragma unroll
        for (int tn = 0; tn < 2; tn++) {
            accP[tn] = (float4v){0.f, 0.f, 0.f, 0.f};
            accG[tn] = (float4v){0.f, 0.f, 0.f, 0.f};
        }
        short8 z8 = (short8){0, 0, 0, 0, 0, 0, 0, 0};
        #pragma unroll
        for (int s = 0; s < 4; s++) {
            short8 aHh = z8, aHl = z8, aSh = z8, aSl = z8;
            if (c16 < 4) {
                int off = c16 * 136 + s * 32 + q * 8;
                aHh = *(const short8*)&sHhi[off];
                aHl = *(const short8*)&sHlo[off];
                aSh = *(const short8*)&sShi[off];
                aSl = *(const short8*)&sSlo[off];
            }
            #pragma unroll
            for (int tn = 0; tn < 2; tn++) {
                int bi = ((2 * w + tn) * 4 + s) * 64 + lane;
                short8 bA = pkA[bi], bB = pkB[bi], bC = pkC[bi];
                accP[tn] = __builtin_amdgcn_mfma_f32_16x16x32_bf16(aHl, bA, accP[tn], 0, 0, 0);
                accP[tn] = __builtin_amdgcn_mfma_f32_16x16x32_bf16(aHh, bA, accP[tn], 0, 0, 0);
                accG[tn] = __builtin_amdgcn_mfma_f32_16x16x32_bf16(aHl, bB, accG[tn], 0, 0, 0);
                accG[tn] = __builtin_amdgcn_mfma_f32_16x16x32_bf16(aHh, bB, accG[tn], 0, 0, 0);
                accG[tn] = __builtin_amdgcn_mfma_f32_16x16x32_bf16(aSl, bC, accG[tn], 0, 0, 0);
                accG[tn] = __builtin_amdgcn_mfma_f32_16x16x32_bf16(aSh, bC, accG[tn], 0, 0, 0);
            }
        }
        if (lane < 16) {
            #pragma unroll
            for (int tn = 0; tn < 2; tn++) {
                int col = (2 * w + tn) * 16 + lane;
                float b1v = Lb1[(l + 1) * 128 + col];
                #pragma unroll
                for (int r = 0; r < 4; r++) {
                    Pnext[(size_t)(nb + r) * 128 + col] = accP[tn][r] + b1v;
                    Gnext[(size_t)(nb + r) * 128 + col] = accG[tn][r];
                }
            }
        }
    }
}

extern "C" void kernel_launch(void* const* d_in, const int* in_sizes, int n_in,
                              void* d_out, int out_size, void* d_ws, size_t ws_size,
                              hipStream_t stream) {
    const float* V     = (const float*)d_in[0];
    const float* E     = (const float*)d_in[1];
    const float* hS    = (const float*)d_in[2];
    const int*   Eidx  = (const int*)d_in[3];
    const float* maskp = (const float*)d_in[4];
    const float* Wv_w  = (const float*)d_in[5];
    const float* Wv_b  = (const float*)d_in[6];
    const float* Wv_g  = (const float*)d_in[7];
    const float* Wv_b2 = (const float*)d_in[8];
    const float* We_w  = (const float*)d_in[9];
    const float* We_b  = (const float*)d_in[10];
    const float* We_g  = (const float*)d_in[11];
    const float* We_b2 = (const float*)d_in[12];
    const float* Lw1   = (const float*)d_in[13];
    const float* Lb1   = (const float*)d_in[14];
    const float* Lw2   = (const float*)d_in[15];
    const float* Lb2   = (const float*)d_in[16];
    const float* Lw3   = (const float*)d_in[17];
    const float* Lb3   = (const float*)d_in[18];
    const float* Ln_g  = (const float*)d_in[19];
    const float* Ln_b  = (const float*)d_in[20];

    char* ws = (char*)d_ws;
    float* h    = (float*)ws; ws += (size_t)BN * 128 * 4;
    float* P0   = (float*)ws; ws += (size_t)BN * 128 * 4;
    float* G0   = (float*)ws; ws += (size_t)BN * 128 * 4;
    float* P1   = (float*)ws; ws += (size_t)BN * 128 * 4;
    float* G1   = (float*)ws; ws += (size_t)BN * 128 * 4;
    u16*   he   = (u16*)ws;   ws += (size_t)NEDGE * 128 * 2;
    u16*   pack = (u16*)ws;   ws += (size_t)15 * 16384 * 2;

    k_setup<<<1551, 256, 0, stream>>>(V, E, hS, Wv_w, Wv_b, Wv_g, Wv_b2,
                                      We_w, We_b, We_g, We_b2, Lw1, Lb1, Lw2, Lw3,
                                      h, he, pack, P0, G0);
    for (int l = 0; l < 3; l++) {
        const float* Pc = (l & 1) ? P1 : P0;
        const float* Gc = (l & 1) ? G1 : G0;
        float* Pn = (l & 1) ? P0 : P1;
        float* Gn = (l & 1) ? G0 : G1;
        k_edge_mlp<<<BN / 4, 256, 0, stream>>>(he, Pc, Gc, Pn, Gn,
                                               Eidx, maskp, pack, Lb2,
                                               Lb3, Ln_g, Ln_b, Lb1, hS, l,
                                               h, (float*)d_out, l == 2);
    }
}